// Round 10
// baseline (102.062 us; speedup 1.0000x reference)
//
#include <hip/hip_runtime.h>
#include <hip/hip_bf16.h>

typedef __bf16 bf16x8 __attribute__((ext_vector_type(8)));
typedef float  f32x4  __attribute__((ext_vector_type(4)));

#define NN 4096
#define DK 128
#define NMAX 0.99f
#define LN2F 0.69314718056f

// frag-major bf16 image, per batch (1 MB): [rowblk 0..255][ks 0..3] -> 1 KB frag
//   chunk for (row gr, k=ks*32+kg*8) at byte ((gr>>4)*4+ks)*1024 + kg*256 + (gr&15)*16
//   (reader: frag_base + lane*16, lane = kg*16 + r16)
// ws layout: XI (4MB) | YI (4MB) | XC (128KB float2: xs, ln(1-xs)) | YC (128KB)
#define WS_XI   0
#define WS_YI   (4u*NN*DK*2u)
#define WS_XC   (2u*WS_YI)
#define WS_YC   (WS_XC + 4u*NN*8u)
#define WS_REQ  (WS_YC + 4u*NN*8u)

// ---------------- pre-pass: f32 -> frag-major bf16 image + (xs, ln(1-xs)) -----
__global__ __launch_bounds__(256)
void prep_kernel(const float* __restrict__ X, const float* __restrict__ Y,
                 __bf16* __restrict__ XI, __bf16* __restrict__ YI,
                 float2* __restrict__ XC, float2* __restrict__ YC)
{
    const int tid = threadIdx.x;
    const int c16 = tid & 15;                 // 8-elem k-chunk index
    const int rl  = tid >> 4;                 // 16 rows per block
    const int gr  = blockIdx.x * 16 + rl;     // row across all batches

    const float* src = blockIdx.y ? Y : X;
    __bf16*      dst = blockIdx.y ? YI : XI;
    float2*      nc  = blockIdx.y ? YC : XC;

    const f32x4* s4 = (const f32x4*)(src + (size_t)gr * DK + c16 * 8);
    f32x4 v0 = s4[0], v1 = s4[1];
    float s = v0[0]*v0[0] + v0[1]*v0[1] + v0[2]*v0[2] + v0[3]*v0[3]
            + v1[0]*v1[0] + v1[1]*v1[1] + v1[2]*v1[2] + v1[3]*v1[3];
    s += __shfl_xor(s, 1);
    s += __shfl_xor(s, 2);
    s += __shfl_xor(s, 4);
    s += __shfl_xor(s, 8);

    bf16x8 pk;
    pk[0]=(__bf16)v0[0]; pk[1]=(__bf16)v0[1]; pk[2]=(__bf16)v0[2]; pk[3]=(__bf16)v0[3];
    pk[4]=(__bf16)v1[0]; pk[5]=(__bf16)v1[1]; pk[6]=(__bf16)v1[2]; pk[7]=(__bf16)v1[3];

    const int bz = gr >> 12;                  // batch
    const int gl = gr & (NN - 1);             // row within batch
    const int ks = c16 >> 2, kg = c16 & 3;
    char* img = (char*)dst + (size_t)bz * (NN * DK * 2);
    const int off = (((gl >> 4) * 4 + ks) << 10) + kg * 256 + (gl & 15) * 16;
    *(bf16x8*)(img + off) = pk;

    if (c16 == 0) nc[gr] = make_float2(s, __logf(1.0f - s));
}

// ---------------- main: NO LDS, NO BARRIERS — fully independent waves --------
// Each wave: 64 output rows x 32 output cols. Block = 4 waves (col slices).
__global__ __launch_bounds__(256, 4)
void hyp_main(const __bf16* __restrict__ XI, const __bf16* __restrict__ YI,
              const float2* __restrict__ XC, const float2* __restrict__ YC,
              float* __restrict__ Out)
{
    const int tid  = threadIdx.x;
    const int lane = tid & 63;
    const int w    = tid >> 6;
    const int bz   = blockIdx.z;
    const int brow = blockIdx.x * 64;              // row-tile fastest
    const int bcol = blockIdx.y * 128 + w * 32;

    const char* ximg = (const char*)XI + (size_t)bz * (NN * DK * 2);
    const char* yimg = (const char*)YI + (size_t)bz * (NN * DK * 2);

    const int xrb = brow >> 4;   // 4 consecutive 16-row x blocks: +i
    const int ycb = bcol >> 4;   // 2 consecutive 16-row y blocks: +j

    // Hoist y-fragments (shared across all 4 row-slabs).
    bf16x8 bg[2][4];
#pragma unroll
    for (int j = 0; j < 2; ++j)
#pragma unroll
        for (int ks = 0; ks < 4; ++ks)
            bg[j][ks] = *(const bf16x8*)(yimg + ((((ycb + j) * 4 + ks) << 10) + lane * 16));

    f32x4 acc[4][2] = {};
#pragma unroll
    for (int ks = 0; ks < 4; ++ks) {
        bf16x8 af[4];
#pragma unroll
        for (int i = 0; i < 4; ++i)
            af[i] = *(const bf16x8*)(ximg + ((((xrb + i) * 4 + ks) << 10) + lane * 16));
        // A=y-frag, B=x-frag: lane's 4 acc regs = 4 consecutive output cols
        // of one output row (verified since R2).
#pragma unroll
        for (int i = 0; i < 4; ++i)
#pragma unroll
            for (int j = 0; j < 2; ++j)
                acc[i][j] = __builtin_amdgcn_mfma_f32_16x16x32_bf16(bg[j][ks], af[i], acc[i][j], 0, 0, 0);
    }

    const int r16 = lane & 15;
    const int kg  = lane >> 4;
    const float2* XCb = XC + bz * NN + brow;
    const float2* YCb = YC + bz * NN + bcol;

    // Hoist per-column (v, ln(1-v)) pairs — shared across the 4 row-slabs.
    f32x4 yv01[2], yv23[2];
#pragma unroll
    for (int j = 0; j < 2; ++j) {
        const int cb = j * 16 + kg * 4;
        yv01[j] = *(const f32x4*)(YCb + cb);       // v0,c0,v1,c1
        yv23[j] = *(const f32x4*)(YCb + cb + 2);   // v2,c2,v3,c3
    }

    // Epilogue: s = u+v-2d, den = 1-2d+uv, den-s = (1-u)(1-v) exactly:
    // out = ln(den + s + 2*sqrt(s*den)) - ln(1-u) - ln(1-v).
#pragma unroll
    for (int i = 0; i < 4; ++i) {
        const int r = i * 16 + r16;
        const float2 xc = XCb[r];
        const float u = xc.x, cx = xc.y;
        float* orow = Out + ((size_t)bz * NN + brow + r) * NN + bcol;
#pragma unroll
        for (int j = 0; j < 2; ++j) {
            const int cb = j * 16 + kg * 4;
            const f32x4 y01 = yv01[j], y23 = yv23[j];
            f32x4 o4;
#pragma unroll
            for (int q = 0; q < 4; ++q) {
                const float d  = acc[i][j][q];
                const float v  = (q < 2) ? y01[2 * q] : y23[2 * (q - 2)];
                const float cy = (q < 2) ? y01[2 * q + 1] : y23[2 * (q - 2) + 1];
                const float e1  = fmaf(-2.0f, d, 1.0f);
                const float den = fmaf(u, v, e1);
                float s = fmaf(-2.0f, d, u + v);
                s = fmaxf(s, 1e-12f);
                const float rt  = __builtin_amdgcn_sqrtf(s * den);
                const float arg = fmaf(2.0f, rt, den + s);
                o4[q] = fmaf(__log2f(arg), LN2F, -(cx + cy));
            }
            __builtin_nontemporal_store(o4, (f32x4*)(orow + cb));
        }
    }
}

// ---------------- fallback (proven R3 structure) if ws is too small ----------
__global__ __launch_bounds__(512, 4)
void hyp_fallback(const float* __restrict__ X, const float* __restrict__ Y,
                  float* __restrict__ Out)
{
    __shared__ alignas(16) __bf16 aL[128 * DK];
    __shared__ alignas(16) __bf16 bL[128 * DK];
    __shared__ float xsL[128];
    __shared__ float ysL[128];

    const int tid  = threadIdx.x;
    const int bz   = blockIdx.z;
    const int brow = blockIdx.y * 128;
    const int bcol = blockIdx.x * 128;
    const float* xb = X + ((size_t)bz * NN + brow) * DK;
    const float* yb = Y + ((size_t)bz * NN + bcol) * DK;
    const int c16 = tid & 15;
    const int rr  = tid >> 4;

#pragma unroll
    for (int p = 0; p < 4; ++p) {
        const int r = p * 32 + rr;
        const f32x4* s4 = (const f32x4*)(xb + r * DK + c16 * 8);
        f32x4 v0 = s4[0], v1 = s4[1];
        float s = v0[0]*v0[0] + v0[1]*v0[1] + v0[2]*v0[2] + v0[3]*v0[3]
                + v1[0]*v1[0] + v1[1]*v1[1] + v1[2]*v1[2] + v1[3]*v1[3];
        s += __shfl_xor(s, 1); s += __shfl_xor(s, 2);
        s += __shfl_xor(s, 4); s += __shfl_xor(s, 8);
        if (c16 == 0) xsL[r] = s;
        bf16x8 pk;
        pk[0]=(__bf16)v0[0]; pk[1]=(__bf16)v0[1]; pk[2]=(__bf16)v0[2]; pk[3]=(__bf16)v0[3];
        pk[4]=(__bf16)v1[0]; pk[5]=(__bf16)v1[1]; pk[6]=(__bf16)v1[2]; pk[7]=(__bf16)v1[3];
        const int byt = (r * 256 + c16 * 16) ^ ((r & 7) << 4);
        *(bf16x8*)((char*)aL + byt) = pk;
    }
#pragma unroll
    for (int p = 0; p < 4; ++p) {
        const int r = p * 32 + rr;
        const f32x4* s4 = (const f32x4*)(yb + r * DK + c16 * 8);
        f32x4 v0 = s4[0], v1 = s4[1];
        float s = v0[0]*v0[0] + v0[1]*v0[1] + v0[2]*v0[2] + v0[3]*v0[3]
                + v1[0]*v1[0] + v1[1]*v1[1] + v1[2]*v1[2] + v1[3]*v1[3];
        s += __shfl_xor(s, 1); s += __shfl_xor(s, 2);
        s += __shfl_xor(s, 4); s += __shfl_xor(s, 8);
        if (c16 == 0) ysL[r] = s;
        bf16x8 pk;
        pk[0]=(__bf16)v0[0]; pk[1]=(__bf16)v0[1]; pk[2]=(__bf16)v0[2]; pk[3]=(__bf16)v0[3];
        pk[4]=(__bf16)v1[0]; pk[5]=(__bf16)v1[1]; pk[6]=(__bf16)v1[2]; pk[7]=(__bf16)v1[3];
        const int byt = (r * 256 + c16 * 16) ^ ((r & 7) << 4);
        *(bf16x8*)((char*)bL + byt) = pk;
    }
    __syncthreads();

    const int lane = tid & 63;
    const int wid  = tid >> 6;
    const int wm   = wid >> 2;
    const int wn   = wid & 3;
    const int r16  = lane & 15;
    const int kg   = lane >> 4;
    f32x4 acc[4][2] = {};
#pragma unroll
    for (int ks = 0; ks < 4; ++ks) {
        const int kb = ks * 32 + kg * 8;
        bf16x8 af[4], bg[2];
#pragma unroll
        for (int i = 0; i < 4; ++i) {
            const int r = wm * 64 + i * 16 + r16;
            const int byt = (r * 256 + kb * 2) ^ ((r & 7) << 4);
            af[i] = *(const bf16x8*)((const char*)aL + byt);
        }
#pragma unroll
        for (int j = 0; j < 2; ++j) {
            const int r = wn * 32 + j * 16 + r16;
            const int byt = (r * 256 + kb * 2) ^ ((r & 7) << 4);
            bg[j] = *(const bf16x8*)((const char*)bL + byt);
        }
#pragma unroll
        for (int i = 0; i < 4; ++i)
#pragma unroll
            for (int j = 0; j < 2; ++j)
                acc[i][j] = __builtin_amdgcn_mfma_f32_16x16x32_bf16(bg[j], af[i], acc[i][j], 0, 0, 0);
    }
    float* ob = Out + ((size_t)bz * NN + brow) * NN + bcol;
#pragma unroll
    for (int i = 0; i < 4; ++i) {
        const int r = wm * 64 + i * 16 + r16;
        const float u = xsL[r];
        float* orow = ob + (size_t)r * NN;
#pragma unroll
        for (int j = 0; j < 2; ++j) {
            const int cb = wn * 32 + j * 16 + kg * 4;
            const f32x4 v4 = *(const f32x4*)&ysL[cb];
            f32x4 o4;
#pragma unroll
            for (int q = 0; q < 4; ++q) {
                const float d  = acc[i][j][q];
                const float v  = v4[q];
                const float e1 = fmaf(-2.0f, d, 1.0f);
                const float den = fmaf(u, v, e1);
                float s = fmaf(-2.0f, d, u + v);
                s = fmaxf(s, 1e-12f);
                const float dn0 = s * __builtin_amdgcn_rsqf(s * den);
                const float dn = fminf(dn0, NMAX);
                o4[q] = __logf((1.0f + dn) * __builtin_amdgcn_rcpf(1.0f - dn));
            }
            *(f32x4*)(orow + cb) = o4;
        }
    }
}

extern "C" void kernel_launch(void* const* d_in, const int* in_sizes, int n_in,
                              void* d_out, int out_size, void* d_ws, size_t ws_size,
                              hipStream_t stream) {
    const float* X = (const float*)d_in[0];
    const float* Y = (const float*)d_in[1];
    float* O = (float*)d_out;
    const int b = in_sizes[0] / (NN * DK);   // = 4

    if (ws_size >= WS_REQ) {
        __bf16* XI = (__bf16*)((char*)d_ws + WS_XI);
        __bf16* YI = (__bf16*)((char*)d_ws + WS_YI);
        float2* XC = (float2*)((char*)d_ws + WS_XC);
        float2* YC = (float2*)((char*)d_ws + WS_YC);
        dim3 pg(b * NN / 16, 2, 1);
        prep_kernel<<<pg, dim3(256), 0, stream>>>(X, Y, XI, YI, XC, YC);
        dim3 grid(NN / 64, NN / 128, b);     // x = row-tile (fast), y = col-tile
        hyp_main<<<grid, dim3(256), 0, stream>>>(XI, YI, XC, YC, O);
    } else {
        dim3 grid(NN / 128, NN / 128, b);
        hyp_fallback<<<grid, dim3(512), 0, stream>>>(X, Y, O);
    }
}

// Round 11
// 72.652 us; speedup vs baseline: 1.4048x; 1.4048x over previous
//
#include <hip/hip_runtime.h>
#include <hip/hip_bf16.h>

typedef __bf16 bf16x8 __attribute__((ext_vector_type(8)));
typedef float  f32x4  __attribute__((ext_vector_type(4)));

#define NN 4096
#define DK 128
#define BM 128
#define BN 128
#define NMAX 0.99f
#define LN2F 0.69314718056f

// ws layout (bytes): 128-row swizzled bf16 tile images + (xs, ln(1-xs)) tables
#define WS_XB   0
#define WS_YB   (4u*4096u*DK*2u)
#define WS_XC   (2u*WS_YB)
#define WS_YC   (WS_XC + 4u*4096u*8u)
#define WS_REQ  (WS_YC + 4u*4096u*8u)

__device__ __forceinline__ void load_lds16(const void* g, void* l) {
    __builtin_amdgcn_global_load_lds(
        (const __attribute__((address_space(1))) unsigned int*)g,
        (__attribute__((address_space(3))) unsigned int*)l, 16, 0, 0);
}

// ---------------- pre-pass: f32 -> swizzled bf16 tile image + (xs, ln(1-xs)) ----
__global__ __launch_bounds__(256)
void prep_kernel(const float* __restrict__ X, const float* __restrict__ Y,
                 __bf16* __restrict__ Xb, __bf16* __restrict__ Yb,
                 float2* __restrict__ XC, float2* __restrict__ YC)
{
    const int tid = threadIdx.x;
    const int c16 = tid & 15;
    const int rl  = tid >> 4;                 // 16 rows per block
    const int gr  = blockIdx.x * 16 + rl;     // row across all batches

    const float* src = blockIdx.y ? Y : X;
    __bf16*      dst = blockIdx.y ? Yb : Xb;
    float2*      nc  = blockIdx.y ? YC : XC;

    const f32x4* s4 = (const f32x4*)(src + (size_t)gr * DK + c16 * 8);
    f32x4 v0 = s4[0], v1 = s4[1];
    float s = v0[0]*v0[0] + v0[1]*v0[1] + v0[2]*v0[2] + v0[3]*v0[3]
            + v1[0]*v1[0] + v1[1]*v1[1] + v1[2]*v1[2] + v1[3]*v1[3];
    s += __shfl_xor(s, 1);
    s += __shfl_xor(s, 2);
    s += __shfl_xor(s, 4);
    s += __shfl_xor(s, 8);

    bf16x8 pk;
    pk[0]=(__bf16)v0[0]; pk[1]=(__bf16)v0[1]; pk[2]=(__bf16)v0[2]; pk[3]=(__bf16)v0[3];
    pk[4]=(__bf16)v1[0]; pk[5]=(__bf16)v1[1]; pk[6]=(__bf16)v1[2]; pk[7]=(__bf16)v1[3];

    const int tile = gr >> 7;                 // 128-row tiles
    const int rloc = gr & 127;
    const int byt  = (rloc * 256 + c16 * 16) ^ ((rloc & 7) << 4);
    *(bf16x8*)((char*)(dst + (size_t)tile * (BM * DK)) + byt) = pk;

    if (c16 == 0) nc[gr] = make_float2(s, __logf(1.0f - s));
}

// ---------------- main: R7 structure + per-slab interleave + XCD swizzle -------
__global__ __launch_bounds__(512, 4)
void hyp_main(const __bf16* __restrict__ Xb, const __bf16* __restrict__ Yb,
              const float2* __restrict__ XC, const float2* __restrict__ YC,
              float* __restrict__ Out)
{
    __shared__ alignas(16) __bf16 aL[BM * DK];   // 32 KB, swizzled image (linear DMA)
    __shared__ alignas(16) __bf16 bL[BN * DK];   // 32 KB
    __shared__ float2 xcL[BM];                   // (xs, ln(1-xs))
    __shared__ float2 ycL[BN];

    // XCD-bijective swizzle over the linear grid (nwg % 8 == 0).
    const int cpx = gridDim.x >> 3;
    const int bid = blockIdx.x;
    const int swz = (bid & 7) * cpx + (bid >> 3);
    const int bx  = swz & 31;                    // col-tile (fastest)
    const int by  = (swz >> 5) & 31;             // row-tile
    const int bz  = swz >> 10;                   // batch

    const int tid  = threadIdx.x;
    const int lane = tid & 63;
    const int wid  = tid >> 6;
    const int brow = by * BM;
    const int bcol = bx * BN;

    const char* xt = (const char*)(Xb + (size_t)(bz * 32 + by) * (BM * DK));
    const char* yt = (const char*)(Yb + (size_t)(bz * 32 + bx) * (BN * DK));

    // Each wave DMAs 4 KB of aL and 4 KB of bL.
    {
        const int woff = wid * 4096;
#pragma unroll
        for (int j = 0; j < 4; ++j) {
            load_lds16(xt + woff + j * 1024 + lane * 16, (char*)aL + woff + j * 1024);
            load_lds16(yt + woff + j * 1024 + lane * 16, (char*)bL + woff + j * 1024);
        }
    }
    if (tid < 128)       xcL[tid]       = XC[bz * NN + brow + tid];
    else if (tid < 256)  ycL[tid - 128] = YC[bz * NN + bcol + (tid - 128)];
    __syncthreads();

    const int wm  = wid >> 2;   // 2x4 wave grid: 64 rows x 32 cols each
    const int wn  = wid & 3;
    const int r16 = lane & 15;
    const int kg  = lane >> 4;

    // Hoist y-fragments once (8 ds_reads, reused by all 4 slabs).
    bf16x8 bg[4][2];
#pragma unroll
    for (int ks = 0; ks < 4; ++ks) {
        const int kb = ks * 32 + kg * 8;
#pragma unroll
        for (int j = 0; j < 2; ++j) {
            const int r = wn * 32 + j * 16 + r16;
            const int byt = (r * 256 + kb * 2) ^ ((r & 7) << 4);
            bg[ks][j] = *(const bf16x8*)((const char*)bL + byt);
        }
    }

    float* ob = Out + ((size_t)bz * NN + brow) * NN + bcol;

    // Per-slab: 4 ds_reads + 8 MFMA + epilogue + 2 stores. Stores issue
    // throughout the compute phase instead of one tail burst.
#pragma unroll
    for (int i = 0; i < 4; ++i) {
        const int r = wm * 64 + i * 16 + r16;
        f32x4 acc[2] = {};
#pragma unroll
        for (int ks = 0; ks < 4; ++ks) {
            const int kb = ks * 32 + kg * 8;
            const int byt = (r * 256 + kb * 2) ^ ((r & 7) << 4);
            const bf16x8 af = *(const bf16x8*)((const char*)aL + byt);
            // A=y-frag, B=x-frag: lane's 4 acc regs = 4 consecutive out cols.
#pragma unroll
            for (int j = 0; j < 2; ++j)
                acc[j] = __builtin_amdgcn_mfma_f32_16x16x32_bf16(bg[ks][j], af, acc[j], 0, 0, 0);
        }

        // Epilogue: s = u+v-2d, den = 1-2d+uv, den-s = (1-u)(1-v) exactly:
        // out = ln(den + s + 2*sqrt(s*den)) - ln(1-u) - ln(1-v).
        const float2 xc = xcL[r];
        const float u = xc.x, cx = xc.y;
        float* orow = ob + (size_t)r * NN;
#pragma unroll
        for (int j = 0; j < 2; ++j) {
            const int cb = wn * 32 + j * 16 + kg * 4;
            const f32x4 y01 = *(const f32x4*)&ycL[cb];       // v0,c0,v1,c1
            const f32x4 y23 = *(const f32x4*)&ycL[cb + 2];   // v2,c2,v3,c3
            f32x4 o4;
#pragma unroll
            for (int q = 0; q < 4; ++q) {
                const float d  = acc[j][q];
                const float v  = (q < 2) ? y01[2 * q] : y23[2 * (q - 2)];
                const float cy = (q < 2) ? y01[2 * q + 1] : y23[2 * (q - 2) + 1];
                const float e1  = fmaf(-2.0f, d, 1.0f);
                const float den = fmaf(u, v, e1);
                float s = fmaf(-2.0f, d, u + v);
                s = fmaxf(s, 1e-12f);
                const float rt  = __builtin_amdgcn_sqrtf(s * den);
                const float arg = fmaf(2.0f, rt, den + s);
                o4[q] = fmaf(__log2f(arg), LN2F, -(cx + cy));
            }
            *(f32x4*)(orow + cb) = o4;
        }
    }
}

// ---------------- fallback (proven R3 structure) if ws is too small ----------
__global__ __launch_bounds__(512, 4)
void hyp_fallback(const float* __restrict__ X, const float* __restrict__ Y,
                  float* __restrict__ Out)
{
    __shared__ alignas(16) __bf16 aL[128 * DK];
    __shared__ alignas(16) __bf16 bL[128 * DK];
    __shared__ float xsL[128];
    __shared__ float ysL[128];

    const int tid  = threadIdx.x;
    const int bz   = blockIdx.z;
    const int brow = blockIdx.y * 128;
    const int bcol = blockIdx.x * 128;
    const float* xb = X + ((size_t)bz * NN + brow) * DK;
    const float* yb = Y + ((size_t)bz * NN + bcol) * DK;
    const int c16 = tid & 15;
    const int rr  = tid >> 4;

#pragma unroll
    for (int p = 0; p < 4; ++p) {
        const int r = p * 32 + rr;
        const f32x4* s4 = (const f32x4*)(xb + r * DK + c16 * 8);
        f32x4 v0 = s4[0], v1 = s4[1];
        float s = v0[0]*v0[0] + v0[1]*v0[1] + v0[2]*v0[2] + v0[3]*v0[3]
                + v1[0]*v1[0] + v1[1]*v1[1] + v1[2]*v1[2] + v1[3]*v1[3];
        s += __shfl_xor(s, 1); s += __shfl_xor(s, 2);
        s += __shfl_xor(s, 4); s += __shfl_xor(s, 8);
        if (c16 == 0) xsL[r] = s;
        bf16x8 pk;
        pk[0]=(__bf16)v0[0]; pk[1]=(__bf16)v0[1]; pk[2]=(__bf16)v0[2]; pk[3]=(__bf16)v0[3];
        pk[4]=(__bf16)v1[0]; pk[5]=(__bf16)v1[1]; pk[6]=(__bf16)v1[2]; pk[7]=(__bf16)v1[3];
        const int byt = (r * 256 + c16 * 16) ^ ((r & 7) << 4);
        *(bf16x8*)((char*)aL + byt) = pk;
    }
#pragma unroll
    for (int p = 0; p < 4; ++p) {
        const int r = p * 32 + rr;
        const f32x4* s4 = (const f32x4*)(yb + r * DK + c16 * 8);
        f32x4 v0 = s4[0], v1 = s4[1];
        float s = v0[0]*v0[0] + v0[1]*v0[1] + v0[2]*v0[2] + v0[3]*v0[3]
                + v1[0]*v1[0] + v1[1]*v1[1] + v1[2]*v1[2] + v1[3]*v1[3];
        s += __shfl_xor(s, 1); s += __shfl_xor(s, 2);
        s += __shfl_xor(s, 4); s += __shfl_xor(s, 8);
        if (c16 == 0) ysL[r] = s;
        bf16x8 pk;
        pk[0]=(__bf16)v0[0]; pk[1]=(__bf16)v0[1]; pk[2]=(__bf16)v0[2]; pk[3]=(__bf16)v0[3];
        pk[4]=(__bf16)v1[0]; pk[5]=(__bf16)v1[1]; pk[6]=(__bf16)v1[2]; pk[7]=(__bf16)v1[3];
        const int byt = (r * 256 + c16 * 16) ^ ((r & 7) << 4);
        *(bf16x8*)((char*)bL + byt) = pk;
    }
    __syncthreads();

    const int lane = tid & 63;
    const int wid  = tid >> 6;
    const int wm   = wid >> 2;
    const int wn   = wid & 3;
    const int r16  = lane & 15;
    const int kg   = lane >> 4;
    f32x4 acc[4][2] = {};
#pragma unroll
    for (int ks = 0; ks < 4; ++ks) {
        const int kb = ks * 32 + kg * 8;
        bf16x8 af[4], bg[2];
#pragma unroll
        for (int i = 0; i < 4; ++i) {
            const int r = wm * 64 + i * 16 + r16;
            const int byt = (r * 256 + kb * 2) ^ ((r & 7) << 4);
            af[i] = *(const bf16x8*)((const char*)aL + byt);
        }
#pragma unroll
        for (int j = 0; j < 2; ++j) {
            const int r = wn * 32 + j * 16 + r16;
            const int byt = (r * 256 + kb * 2) ^ ((r & 7) << 4);
            bg[j] = *(const bf16x8*)((const char*)bL + byt);
        }
#pragma unroll
        for (int i = 0; i < 4; ++i)
#pragma unroll
            for (int j = 0; j < 2; ++j)
                acc[i][j] = __builtin_amdgcn_mfma_f32_16x16x32_bf16(bg[j], af[i], acc[i][j], 0, 0, 0);
    }
    float* ob = Out + ((size_t)bz * NN + brow) * NN + bcol;
#pragma unroll
    for (int i = 0; i < 4; ++i) {
        const int r = wm * 64 + i * 16 + r16;
        const float u = xsL[r];
        float* orow = ob + (size_t)r * NN;
#pragma unroll
        for (int j = 0; j < 2; ++j) {
            const int cb = wn * 32 + j * 16 + kg * 4;
            const f32x4 v4 = *(const f32x4*)&ysL[cb];
            f32x4 o4;
#pragma unroll
            for (int q = 0; q < 4; ++q) {
                const float d  = acc[i][j][q];
                const float v  = v4[q];
                const float e1 = fmaf(-2.0f, d, 1.0f);
                const float den = fmaf(u, v, e1);
                float s = fmaf(-2.0f, d, u + v);
                s = fmaxf(s, 1e-12f);
                const float dn0 = s * __builtin_amdgcn_rsqf(s * den);
                const float dn = fminf(dn0, NMAX);
                o4[q] = __logf((1.0f + dn) * __builtin_amdgcn_rcpf(1.0f - dn));
            }
            *(f32x4*)(orow + cb) = o4;
        }
    }
}

extern "C" void kernel_launch(void* const* d_in, const int* in_sizes, int n_in,
                              void* d_out, int out_size, void* d_ws, size_t ws_size,
                              hipStream_t stream) {
    const float* X = (const float*)d_in[0];
    const float* Y = (const float*)d_in[1];
    float* O = (float*)d_out;
    const int b = in_sizes[0] / (NN * DK);   // = 4

    if (ws_size >= WS_REQ) {
        __bf16* Xb = (__bf16*)((char*)d_ws + WS_XB);
        __bf16* Yb = (__bf16*)((char*)d_ws + WS_YB);
        float2* XC = (float2*)((char*)d_ws + WS_XC);
        float2* YC = (float2*)((char*)d_ws + WS_YC);
        dim3 pg(b * NN / 16, 2, 1);
        prep_kernel<<<pg, dim3(256), 0, stream>>>(X, Y, Xb, Yb, XC, YC);
        const int nwg = b * 32 * 32;         // linear grid, XCD-swizzled in-kernel
        hyp_main<<<dim3(nwg), dim3(512), 0, stream>>>(Xb, Yb, XC, YC, O);
    } else {
        dim3 grid(NN / 128, NN / 128, b);
        hyp_fallback<<<grid, dim3(512), 0, stream>>>(X, Y, O);
    }
}

// Round 12
// 66.849 us; speedup vs baseline: 1.5268x; 1.0868x over previous
//
#include <hip/hip_runtime.h>
#include <hip/hip_bf16.h>

typedef __bf16 bf16x8 __attribute__((ext_vector_type(8)));
typedef float  f32x4  __attribute__((ext_vector_type(4)));

#define NN 4096
#define DK 128
#define NMAX 0.99f
#define LN2F 0.69314718056f

// frag-major bf16 image, per batch (1 MB): [rowblk 0..255][ks 0..3] -> 1 KB frag
//   chunk for (row gr, k=ks*32+kg*8) at byte ((gr>>4)*4+ks)*1024 + kg*256 + (gr&15)*16
//   reader: frag_base + lane*16  (lane = kg*16 + r16) — verified R9/R10.
// ws layout: XI (4MB) | YI (4MB) | XC (128KB float2: xs, ln(1-xs)) | YC (128KB)
#define WS_XI   0
#define WS_YI   (4u*NN*DK*2u)
#define WS_XC   (2u*WS_YI)
#define WS_YC   (WS_XC + 4u*NN*8u)
#define WS_REQ  (WS_YC + 4u*NN*8u)

__device__ __forceinline__ void load_lds16(const void* g, void* l) {
    __builtin_amdgcn_global_load_lds(
        (const __attribute__((address_space(1))) unsigned int*)g,
        (__attribute__((address_space(3))) unsigned int*)l, 16, 0, 0);
}

// ---------------- pre-pass: f32 -> frag-major bf16 image + (xs, ln(1-xs)) -----
__global__ __launch_bounds__(256)
void prep_kernel(const float* __restrict__ X, const float* __restrict__ Y,
                 __bf16* __restrict__ XI, __bf16* __restrict__ YI,
                 float2* __restrict__ XC, float2* __restrict__ YC)
{
    const int tid = threadIdx.x;
    const int c16 = tid & 15;                 // 8-elem k-chunk index
    const int rl  = tid >> 4;                 // 16 rows per block
    const int gr  = blockIdx.x * 16 + rl;     // row across all batches

    const float* src = blockIdx.y ? Y : X;
    __bf16*      dst = blockIdx.y ? YI : XI;
    float2*      nc  = blockIdx.y ? YC : XC;

    const f32x4* s4 = (const f32x4*)(src + (size_t)gr * DK + c16 * 8);
    f32x4 v0 = s4[0], v1 = s4[1];
    float s = v0[0]*v0[0] + v0[1]*v0[1] + v0[2]*v0[2] + v0[3]*v0[3]
            + v1[0]*v1[0] + v1[1]*v1[1] + v1[2]*v1[2] + v1[3]*v1[3];
    s += __shfl_xor(s, 1);
    s += __shfl_xor(s, 2);
    s += __shfl_xor(s, 4);
    s += __shfl_xor(s, 8);

    bf16x8 pk;
    pk[0]=(__bf16)v0[0]; pk[1]=(__bf16)v0[1]; pk[2]=(__bf16)v0[2]; pk[3]=(__bf16)v0[3];
    pk[4]=(__bf16)v1[0]; pk[5]=(__bf16)v1[1]; pk[6]=(__bf16)v1[2]; pk[7]=(__bf16)v1[3];

    const int bz = gr >> 12;                  // batch
    const int gl = gr & (NN - 1);             // row within batch
    const int ks = c16 >> 2, kg = c16 & 3;
    char* img = (char*)dst + (size_t)bz * (NN * DK * 2);
    const int off = (((gl >> 4) * 4 + ks) << 10) + kg * 256 + (gl & 15) * 16;
    *(bf16x8*)(img + off) = pk;

    if (c16 == 0) nc[gr] = make_float2(s, __logf(1.0f - s));
}

// ---------------- main: 128x128, x via LDS DMA, y-frags in registers ----------
// LDS 34 KB -> 4 blocks/CU (32 waves/CU). One barrier per block.
__global__ __launch_bounds__(512, 4)
void hyp_main(const __bf16* __restrict__ XI, const __bf16* __restrict__ YI,
              const float2* __restrict__ XC, const float2* __restrict__ YC,
              float* __restrict__ Out)
{
    __shared__ alignas(16) char aL[32 * 1024];   // x-tile frag-major image
    __shared__ float2 xcL[128];                  // (xs, ln(1-xs))
    __shared__ float2 ycL[128];

    // XCD-bijective swizzle over the linear grid (nwg = 4096, %8 == 0).
    const int cpx = gridDim.x >> 3;
    const int bid = blockIdx.x;
    const int swz = (bid & 7) * cpx + (bid >> 3);
    const int bx  = swz & 31;                    // col-tile (fastest)
    const int by  = (swz >> 5) & 31;             // row-tile
    const int bz  = swz >> 10;                   // batch

    const int tid  = threadIdx.x;
    const int lane = tid & 63;
    const int wid  = tid >> 6;
    const int brow = by * 128;
    const int bcol = bx * 128;

    const char* ximg = (const char*)XI + (size_t)bz * (NN * DK * 2);
    const char* yimg = (const char*)YI + (size_t)bz * (NN * DK * 2);

    // DMA the 32 KB x row-tile image into LDS (linear, conflict-free).
    {
        const char* xt = ximg + ((size_t)(brow >> 4) << 12);
        const int woff = wid * 4096;
#pragma unroll
        for (int p = 0; p < 4; ++p)
            load_lds16(xt + woff + p * 1024 + lane * 16, aL + woff + p * 1024);
    }
    if (tid < 128)       xcL[tid]       = XC[bz * NN + brow + tid];
    else if (tid < 256)  ycL[tid - 128] = YC[bz * NN + bcol + (tid - 128)];

    const int wm  = wid >> 2;   // 2x4 wave grid: 64 rows x 32 cols each
    const int wn  = wid & 3;
    const int r16 = lane & 15;
    const int kg  = lane >> 4;

    // Hoist y-fragments from global image (8 coalesced 1 KB loads / wave,
    // independent of the barrier, off the inner loop).
    bf16x8 bg[4][2];
    const int ycb = (bcol >> 4) + wn * 2;
#pragma unroll
    for (int ks = 0; ks < 4; ++ks)
#pragma unroll
        for (int j = 0; j < 2; ++j)
            bg[ks][j] = *(const bf16x8*)(yimg + ((((ycb + j) * 4 + ks) << 10) + lane * 16));

    __syncthreads();   // drain x-DMA + table writes

    float* ob = Out + ((size_t)bz * NN + brow) * NN + bcol;

    // Per-slab: 4 ds_reads + 8 MFMA + epilogue + 2 stores.
#pragma unroll
    for (int i = 0; i < 4; ++i) {
        const int rb = wm * 4 + i;         // local 16-rowblock
        f32x4 acc[2] = {};
#pragma unroll
        for (int ks = 0; ks < 4; ++ks) {
            const bf16x8 af = *(const bf16x8*)(aL + (((rb * 4 + ks) << 10) + lane * 16));
            // A=y-frag, B=x-frag: lane's 4 acc regs = 4 consecutive out cols.
#pragma unroll
            for (int j = 0; j < 2; ++j)
                acc[j] = __builtin_amdgcn_mfma_f32_16x16x32_bf16(bg[ks][j], af, acc[j], 0, 0, 0);
        }

        // Epilogue: s = u+v-2d, den = 1-2d+uv, den-s = (1-u)(1-v) exactly:
        // out = ln(den + s + 2*sqrt(s*den)) - ln(1-u) - ln(1-v).
        const int r = wm * 64 + i * 16 + r16;
        const float2 xc = xcL[r];
        const float u = xc.x, cx = xc.y;
        float* orow = ob + (size_t)r * NN;
#pragma unroll
        for (int j = 0; j < 2; ++j) {
            const int cb = wn * 32 + j * 16 + kg * 4;
            const f32x4 y01 = *(const f32x4*)&ycL[cb];       // v0,c0,v1,c1
            const f32x4 y23 = *(const f32x4*)&ycL[cb + 2];   // v2,c2,v3,c3
            f32x4 o4;
#pragma unroll
            for (int q = 0; q < 4; ++q) {
                const float d  = acc[j][q];
                const float v  = (q < 2) ? y01[2 * q] : y23[2 * (q - 2)];
                const float cy = (q < 2) ? y01[2 * q + 1] : y23[2 * (q - 2) + 1];
                const float e1  = fmaf(-2.0f, d, 1.0f);
                const float den = fmaf(u, v, e1);
                float s = fmaf(-2.0f, d, u + v);
                s = fmaxf(s, 1e-12f);
                const float rt  = __builtin_amdgcn_sqrtf(s * den);
                const float arg = fmaf(2.0f, rt, den + s);
                o4[q] = fmaf(__log2f(arg), LN2F, -(cx + cy));
            }
            *(f32x4*)(orow + cb) = o4;
        }
    }
}

// ---------------- fallback (proven R3 structure) if ws is too small ----------
__global__ __launch_bounds__(512, 4)
void hyp_fallback(const float* __restrict__ X, const float* __restrict__ Y,
                  float* __restrict__ Out)
{
    __shared__ alignas(16) __bf16 aL[128 * DK];
    __shared__ alignas(16) __bf16 bL[128 * DK];
    __shared__ float xsL[128];
    __shared__ float ysL[128];

    const int tid  = threadIdx.x;
    const int bz   = blockIdx.z;
    const int brow = blockIdx.y * 128;
    const int bcol = blockIdx.x * 128;
    const float* xb = X + ((size_t)bz * NN + brow) * DK;
    const float* yb = Y + ((size_t)bz * NN + bcol) * DK;
    const int c16 = tid & 15;
    const int rr  = tid >> 4;

#pragma unroll
    for (int p = 0; p < 4; ++p) {
        const int r = p * 32 + rr;
        const f32x4* s4 = (const f32x4*)(xb + r * DK + c16 * 8);
        f32x4 v0 = s4[0], v1 = s4[1];
        float s = v0[0]*v0[0] + v0[1]*v0[1] + v0[2]*v0[2] + v0[3]*v0[3]
                + v1[0]*v1[0] + v1[1]*v1[1] + v1[2]*v1[2] + v1[3]*v1[3];
        s += __shfl_xor(s, 1); s += __shfl_xor(s, 2);
        s += __shfl_xor(s, 4); s += __shfl_xor(s, 8);
        if (c16 == 0) xsL[r] = s;
        bf16x8 pk;
        pk[0]=(__bf16)v0[0]; pk[1]=(__bf16)v0[1]; pk[2]=(__bf16)v0[2]; pk[3]=(__bf16)v0[3];
        pk[4]=(__bf16)v1[0]; pk[5]=(__bf16)v1[1]; pk[6]=(__bf16)v1[2]; pk[7]=(__bf16)v1[3];
        const int byt = (r * 256 + c16 * 16) ^ ((r & 7) << 4);
        *(bf16x8*)((char*)aL + byt) = pk;
    }
#pragma unroll
    for (int p = 0; p < 4; ++p) {
        const int r = p * 32 + rr;
        const f32x4* s4 = (const f32x4*)(yb + r * DK + c16 * 8);
        f32x4 v0 = s4[0], v1 = s4[1];
        float s = v0[0]*v0[0] + v0[1]*v0[1] + v0[2]*v0[2] + v0[3]*v0[3]
                + v1[0]*v1[0] + v1[1]*v1[1] + v1[2]*v1[2] + v1[3]*v1[3];
        s += __shfl_xor(s, 1); s += __shfl_xor(s, 2);
        s += __shfl_xor(s, 4); s += __shfl_xor(s, 8);
        if (c16 == 0) ysL[r] = s;
        bf16x8 pk;
        pk[0]=(__bf16)v0[0]; pk[1]=(__bf16)v0[1]; pk[2]=(__bf16)v0[2]; pk[3]=(__bf16)v0[3];
        pk[4]=(__bf16)v1[0]; pk[5]=(__bf16)v1[1]; pk[6]=(__bf16)v1[2]; pk[7]=(__bf16)v1[3];
        const int byt = (r * 256 + c16 * 16) ^ ((r & 7) << 4);
        *(bf16x8*)((char*)bL + byt) = pk;
    }
    __syncthreads();

    const int lane = tid & 63;
    const int wid  = tid >> 6;
    const int wm   = wid >> 2;
    const int wn   = wid & 3;
    const int r16  = lane & 15;
    const int kg   = lane >> 4;
    f32x4 acc[4][2] = {};
#pragma unroll
    for (int ks = 0; ks < 4; ++ks) {
        const int kb = ks * 32 + kg * 8;
        bf16x8 af[4], bg[2];
#pragma unroll
        for (int i = 0; i < 4; ++i) {
            const int r = wm * 64 + i * 16 + r16;
            const int byt = (r * 256 + kb * 2) ^ ((r & 7) << 4);
            af[i] = *(const bf16x8*)((const char*)aL + byt);
        }
#pragma unroll
        for (int j = 0; j < 2; ++j) {
            const int r = wn * 32 + j * 16 + r16;
            const int byt = (r * 256 + kb * 2) ^ ((r & 7) << 4);
            bg[j] = *(const bf16x8*)((const char*)bL + byt);
        }
#pragma unroll
        for (int i = 0; i < 4; ++i)
#pragma unroll
            for (int j = 0; j < 2; ++j)
                acc[i][j] = __builtin_amdgcn_mfma_f32_16x16x32_bf16(bg[j], af[i], acc[i][j], 0, 0, 0);
    }
    float* ob = Out + ((size_t)bz * NN + brow) * NN + bcol;
#pragma unroll
    for (int i = 0; i < 4; ++i) {
        const int r = wm * 64 + i * 16 + r16;
        const float u = xsL[r];
        float* orow = ob + (size_t)r * NN;
#pragma unroll
        for (int j = 0; j < 2; ++j) {
            const int cb = wn * 32 + j * 16 + kg * 4;
            const f32x4 v4 = *(const f32x4*)&ysL[cb];
            f32x4 o4;
#pragma unroll
            for (int q = 0; q < 4; ++q) {
                const float d  = acc[i][j][q];
                const float v  = v4[q];
                const float e1 = fmaf(-2.0f, d, 1.0f);
                const float den = fmaf(u, v, e1);
                float s = fmaf(-2.0f, d, u + v);
                s = fmaxf(s, 1e-12f);
                const float dn0 = s * __builtin_amdgcn_rsqf(s * den);
                const float dn = fminf(dn0, NMAX);
                o4[q] = __logf((1.0f + dn) * __builtin_amdgcn_rcpf(1.0f - dn));
            }
            *(f32x4*)(orow + cb) = o4;
        }
    }
}

extern "C" void kernel_launch(void* const* d_in, const int* in_sizes, int n_in,
                              void* d_out, int out_size, void* d_ws, size_t ws_size,
                              hipStream_t stream) {
    const float* X = (const float*)d_in[0];
    const float* Y = (const float*)d_in[1];
    float* O = (float*)d_out;
    const int b = in_sizes[0] / (NN * DK);   // = 4

    if (ws_size >= WS_REQ) {
        __bf16* XI = (__bf16*)((char*)d_ws + WS_XI);
        __bf16* YI = (__bf16*)((char*)d_ws + WS_YI);
        float2* XC = (float2*)((char*)d_ws + WS_XC);
        float2* YC = (float2*)((char*)d_ws + WS_YC);
        dim3 pg(b * NN / 16, 2, 1);
        prep_kernel<<<pg, dim3(256), 0, stream>>>(X, Y, XI, YI, XC, YC);
        const int nwg = b * 32 * 32;         // 4096, XCD-swizzled in-kernel
        hyp_main<<<dim3(nwg), dim3(512), 0, stream>>>(XI, YI, XC, YC, O);
    } else {
        dim3 grid(NN / 128, NN / 128, b);
        hyp_fallback<<<grid, dim3(512), 0, stream>>>(X, Y, O);
    }
}